// Round 1
// baseline (1672.462 us; speedup 1.0000x reference)
//
#include <hip/hip_runtime.h>

// ---------------------------------------------------------------------------
// DenoiseGCN fused kernel for MI355X (gfx950).
// Strategy: one fused kernel per (batch, 64-vertex tile) with halo=4 rings.
// All activations live in LDS (bf16, XOR-swizzled); all matmuls via
// v_mfma_f32_16x16x32_bf16; weights pre-transposed to [N][K] bf16 in d_ws
// (L2-resident). Output fp32.
// ---------------------------------------------------------------------------

typedef __attribute__((ext_vector_type(8))) short bf16x8;
typedef __attribute__((ext_vector_type(4))) float f32x4;

#define NV 1024

// ws element offsets (bf16 elements)
#define OFF_W0T   0        // [256][160]
#define OFF_RES0T 40960    // [256][160]
#define OFF_W1T   81920    // [256][256]
#define OFF_W2T   147456
#define OFF_W3T   212992
#define OFF_HW1T  278528
#define OFF_HW2T  344064   // [16][256]
#define OFF_TEMB  348160   // [512][128]
#define PREP_ELEMS 348160

__device__ __forceinline__ float bf2f(short u){
  union { unsigned int i; float f; } v;
  v.i = ((unsigned int)(unsigned short)u) << 16;
  return v.f;
}
__device__ __forceinline__ short f2bf(float f){
  union { float f; unsigned int i; } v; v.f = f;
  unsigned int r = v.i + 0x7FFFu + ((v.i >> 16) & 1u);   // RNE
  return (short)(r >> 16);
}
__device__ __forceinline__ float silu_f(float v){
  return v / (1.f + __expf(-v));
}
__device__ __forceinline__ int swz(int row, int cb){
  // 16B-granularity XOR swizzle: breaks the 512B-row-stride bank conflict
  return cb ^ ((row & 7) << 4);
}

// ---------------------------------------------------------------------------
// prep: fp32 weights -> bf16, transposed to [N][K] (k contiguous) with pads.
// Layer-0 K order permuted to [temb(128), coords(2), zeros(30)] so that LDS
// h0 staging is 16B-aligned (temb at col 0, coords at col 128).
// ---------------------------------------------------------------------------
__global__ void prep_kernel(const float* __restrict__ W0, const float* __restrict__ res0,
                            const float* __restrict__ W1, const float* __restrict__ W2,
                            const float* __restrict__ W3, const float* __restrict__ hW1,
                            const float* __restrict__ hW2, short* __restrict__ ws){
  int idx = blockIdx.x * 256 + threadIdx.x;
  if (idx >= PREP_ELEMS) return;
  float v = 0.f;
  if (idx < 81920){
    const float* src = (idx < 40960) ? W0 : res0;
    int rem = (idx < 40960) ? idx : idx - 40960;
    int n = rem / 160, k = rem - n * 160;
    if (k < 130){
      int sk = (k < 128) ? (k + 2) : (k - 128);  // temb rows first, coords last
      v = src[sk * 256 + n];
    }
  } else if (idx < 344064){
    int rem = idx - 81920;
    int seg = rem >> 16;
    int r2 = rem & 65535;
    int n = r2 >> 8, k = r2 & 255;
    const float* src = (seg == 0) ? W1 : (seg == 1) ? W2 : (seg == 2) ? W3 : hW1;
    v = src[k * 256 + n];
  } else {
    int rem = idx - 344064;
    int n = rem >> 8, k = rem & 255;
    if (n < 2) v = hW2[k * 2 + n];
  }
  ws[idx] = f2bf(v);
}

// ---------------------------------------------------------------------------
// temb: silu(sinusoidal(t) @ time_W + time_b) per batch element -> bf16
// ---------------------------------------------------------------------------
__global__ void temb_kernel(const int* __restrict__ t, const float* __restrict__ tW,
                            const float* __restrict__ tb, short* __restrict__ temb){
  __shared__ float sc[128];
  int b = blockIdx.x, n = threadIdx.x;  // 128 threads
  float tv = (float)t[b];
  {
    int j = n & 63;
    float fr = __expf(-9.210340371976184f * (float)j * (1.f / 63.f));
    float ang = tv * fr;
    sc[n] = (n < 64) ? sinf(ang) : cosf(ang);
  }
  __syncthreads();
  float acc = tb[n];
  #pragma unroll 8
  for (int k = 0; k < 128; ++k) acc += sc[k] * tW[k * 128 + n];
  temb[b * 128 + n] = f2bf(silu_f(acc));
}

// ---------------------------------------------------------------------------
// MFMA tile matmul: g[0:80][n0:n0+64] = hbuf[0:80][0:KPAD] @ Wt^T
// Wt layout [N][KPAD] row-major, bf16.  A-frag: row=l&15, k=(l>>4)*8+j.
// B-frag: col=l&15, k=(l>>4)*8+j.  C: col=l&15, row=(l>>4)*4+j.
// ---------------------------------------------------------------------------
template<int KPAD>
__device__ __forceinline__ void mm_tiles(const char* hb, const short* __restrict__ Wt,
                                         int lane, int n0, f32x4 acc[5][4]){
  const int m15 = lane & 15, kb = lane >> 4;
  const short* wb = Wt + (n0 + m15) * KPAD + kb * 8;
  #pragma unroll
  for (int ks = 0; ks < KPAD / 32; ++ks){
    bf16x8 bfr[4];
    #pragma unroll
    for (int nt = 0; nt < 4; ++nt)
      bfr[nt] = *(const bf16x8*)(wb + nt * 16 * KPAD + ks * 32);
    const int kbyte = ks * 64 + kb * 16;
    bf16x8 afr[5];
    #pragma unroll
    for (int mt = 0; mt < 5; ++mt){
      int row = mt * 16 + m15;
      afr[mt] = *(const bf16x8*)(hb + row * 512 + swz(row, kbyte));
    }
    #pragma unroll
    for (int mt = 0; mt < 5; ++mt)
      #pragma unroll
      for (int nt = 0; nt < 4; ++nt)
        acc[mt][nt] = __builtin_amdgcn_mfma_f32_16x16x32_bf16(afr[mt], bfr[nt], acc[mt][nt], 0, 0, 0);
  }
}

// ---------------------------------------------------------------------------
// Fused GCN. Grid (16, 512): blockIdx.x = vertex tile, blockIdx.y = batch.
// 256 threads = 4 waves; wave w owns output columns [64w, 64w+64).
// LDS: hbuf 80x256 bf16 (40960B) + gbuf 80x256 bf16 (40960B) = 80KiB -> 2 blk/CU.
// Row r <-> vertex (v0 + r - 4) mod 1024. Valid windows shrink by 1/layer:
// h0:0..71, h1:1..70, h2:2..69, h3:3..68, h4:4..67.
// ---------------------------------------------------------------------------
__global__ __launch_bounds__(256, 2)
void gcn_fused(const float* __restrict__ x, const short* __restrict__ ws,
               const float* __restrict__ b0, const float* __restrict__ b1,
               const float* __restrict__ b2, const float* __restrict__ b3,
               const float* __restrict__ hb1, const float* __restrict__ hb2,
               float* __restrict__ out){
  extern __shared__ char lds[];
  char* hb = lds;
  char* gb = lds + 40960;
  const int tid = threadIdx.x, lane = tid & 63, wid = tid >> 6;
  const int m15 = lane & 15, kb = lane >> 4, rbase = kb * 4;
  const int n0 = wid * 64;
  const int b = blockIdx.y, v0 = blockIdx.x * 64;

  // ---- stage h0 ----
  #pragma unroll
  for (int off = 0; off < 40960; off += 4096){
    bf16x8 z = {0, 0, 0, 0, 0, 0, 0, 0};
    *(bf16x8*)(hb + off + tid * 16) = z;
  }
  __syncthreads();
  const short* tembp = ws + OFF_TEMB + b * 128;
  for (int task = tid; task < 72 * 16; task += 256){
    int r = task >> 4, ck = task & 15;
    bf16x8 v = *(const bf16x8*)(tembp + ck * 8);
    *(bf16x8*)(hb + r * 512 + swz(r, ck * 16)) = v;
  }
  for (int r = tid; r < 72; r += 256){
    int v = (v0 + r - 4) & (NV - 1);
    const float* cp = x + b * 2048 + v * 2;
    unsigned int pk = (unsigned int)(unsigned short)f2bf(cp[0])
                    | (((unsigned int)(unsigned short)f2bf(cp[1])) << 16);
    *(unsigned int*)(hb + r * 512 + swz(r, 256)) = pk;  // cols 128,129
  }
  __syncthreads();

  // ---- layer 0: g = h0@W0 ; r0 = h0@res0 (kept in regs) ; agg+bias+res+silu ----
  {
    f32x4 acc[5][4];
    #pragma unroll
    for (int i = 0; i < 5; ++i)
      #pragma unroll
      for (int j = 0; j < 4; ++j){ f32x4 z = {0.f,0.f,0.f,0.f}; acc[i][j] = z; }
    mm_tiles<160>(hb, ws + OFF_W0T, lane, n0, acc);
    #pragma unroll
    for (int mt = 0; mt < 5; ++mt)
      #pragma unroll
      for (int nt = 0; nt < 4; ++nt){
        int cb = (n0 + nt * 16 + m15) * 2;
        #pragma unroll
        for (int j = 0; j < 4; ++j){
          int row = mt * 16 + rbase + j;
          *(short*)(gb + row * 512 + swz(row, cb)) = f2bf(acc[mt][nt][j]);
        }
      }
    __syncthreads();

    f32x4 accr[5][4];
    #pragma unroll
    for (int i = 0; i < 5; ++i)
      #pragma unroll
      for (int j = 0; j < 4; ++j){ f32x4 z = {0.f,0.f,0.f,0.f}; accr[i][j] = z; }
    mm_tiles<160>(hb, ws + OFF_RES0T, lane, n0, accr);
    __syncthreads();  // all reads of hbuf done before we overwrite it

    #pragma unroll
    for (int mt = 0; mt < 5; ++mt)
      #pragma unroll
      for (int nt = 0; nt < 4; ++nt){
        int col = n0 + nt * 16 + m15;
        float bias = b0[col];
        int cb = col * 2;
        #pragma unroll
        for (int j = 0; j < 4; ++j){
          int row = mt * 16 + rbase + j;
          if (row >= 1 && row < 71){
            float g3 = bf2f(*(const short*)(gb + (row - 1) * 512 + swz(row - 1, cb)))
                     + bf2f(*(const short*)(gb + (row    ) * 512 + swz(row,     cb)))
                     + bf2f(*(const short*)(gb + (row + 1) * 512 + swz(row + 1, cb)));
            float s = g3 * (1.f / 3.f) + bias + accr[mt][nt][j];
            *(short*)(hb + row * 512 + swz(row, cb)) = f2bf(silu_f(s));
          }
        }
      }
    __syncthreads();
  }

  // ---- layers 1..3: g = h@W ; h = silu(agg(g) + b + h) ----
  {
    const short* Wts[3] = {ws + OFF_W1T, ws + OFF_W2T, ws + OFF_W3T};
    const float* bss[3] = {b1, b2, b3};
    #pragma unroll
    for (int L = 0; L < 3; ++L){
      f32x4 acc[5][4];
      #pragma unroll
      for (int i = 0; i < 5; ++i)
        #pragma unroll
        for (int j = 0; j < 4; ++j){ f32x4 z = {0.f,0.f,0.f,0.f}; acc[i][j] = z; }
      mm_tiles<256>(hb, Wts[L], lane, n0, acc);
      #pragma unroll
      for (int mt = 0; mt < 5; ++mt)
        #pragma unroll
        for (int nt = 0; nt < 4; ++nt){
          int cb = (n0 + nt * 16 + m15) * 2;
          #pragma unroll
          for (int j = 0; j < 4; ++j){
            int row = mt * 16 + rbase + j;
            *(short*)(gb + row * 512 + swz(row, cb)) = f2bf(acc[mt][nt][j]);
          }
        }
      __syncthreads();

      const int lo = L + 2, nrows = 68 - 2 * L;
      const float* bias = bss[L];
      for (int task = tid; task < nrows * 32; task += 256){
        int r = lo + (task >> 5), ck = task & 31, cb = ck * 16;
        bf16x8 gm = *(const bf16x8*)(gb + (r - 1) * 512 + swz(r - 1, cb));
        bf16x8 gc = *(const bf16x8*)(gb + (r    ) * 512 + swz(r,     cb));
        bf16x8 gp = *(const bf16x8*)(gb + (r + 1) * 512 + swz(r + 1, cb));
        bf16x8 hr = *(const bf16x8*)(hb + r * 512 + swz(r, cb));
        f32x4 bA = *(const f32x4*)(bias + ck * 8);
        f32x4 bB = *(const f32x4*)(bias + ck * 8 + 4);
        bf16x8 o;
        #pragma unroll
        for (int e = 0; e < 8; ++e){
          float s = (bf2f(gm[e]) + bf2f(gc[e]) + bf2f(gp[e])) * (1.f / 3.f)
                  + ((e < 4) ? bA[e] : bB[e - 4]) + bf2f(hr[e]);
          o[e] = f2bf(silu_f(s));
        }
        *(bf16x8*)(hb + r * 512 + swz(r, cb)) = o;
      }
      __syncthreads();
    }
  }

  // ---- head part 1: u = silu(h4 @ hW1 + hb1), in-place (rows 4..67) ----
  {
    f32x4 acc[5][4];
    #pragma unroll
    for (int i = 0; i < 5; ++i)
      #pragma unroll
      for (int j = 0; j < 4; ++j){ f32x4 z = {0.f,0.f,0.f,0.f}; acc[i][j] = z; }
    mm_tiles<256>(hb, ws + OFF_HW1T, lane, n0, acc);
    __syncthreads();  // all hbuf reads done
    #pragma unroll
    for (int mt = 0; mt < 5; ++mt)
      #pragma unroll
      for (int nt = 0; nt < 4; ++nt){
        int col = n0 + nt * 16 + m15;
        float bias = hb1[col];
        int cb = col * 2;
        #pragma unroll
        for (int j = 0; j < 4; ++j){
          int row = mt * 16 + rbase + j;
          if (row >= 4 && row < 68)
            *(short*)(hb + row * 512 + swz(row, cb)) = f2bf(silu_f(acc[mt][nt][j] + bias));
        }
      }
    __syncthreads();
  }

  // ---- head part 2: out = u @ hW2 + hb2 (N padded 2->16; all waves compute,
  //      wave 0 writes) ----
  {
    f32x4 acc2[5];
    #pragma unroll
    for (int i = 0; i < 5; ++i){ f32x4 z = {0.f,0.f,0.f,0.f}; acc2[i] = z; }
    const short* wb = ws + OFF_HW2T + m15 * 256 + kb * 8;
    #pragma unroll
    for (int ks = 0; ks < 8; ++ks){
      bf16x8 bfr = *(const bf16x8*)(wb + ks * 32);
      int kbyte = ks * 64 + kb * 16;
      #pragma unroll
      for (int mt = 0; mt < 5; ++mt){
        int row = mt * 16 + m15;
        bf16x8 afr = *(const bf16x8*)(hb + row * 512 + swz(row, kbyte));
        acc2[mt] = __builtin_amdgcn_mfma_f32_16x16x32_bf16(afr, bfr, acc2[mt], 0, 0, 0);
      }
    }
    if (wid == 0 && m15 < 2){
      float bias = hb2[m15];
      #pragma unroll
      for (int mt = 0; mt < 5; ++mt)
        #pragma unroll
        for (int j = 0; j < 4; ++j){
          int row = mt * 16 + rbase + j;
          if (row >= 4 && row < 68)
            out[b * 2048 + (v0 + row - 4) * 2 + m15] = acc2[mt][j] + bias;
        }
    }
  }
}

// ---------------------------------------------------------------------------
extern "C" void kernel_launch(void* const* d_in, const int* in_sizes, int n_in,
                              void* d_out, int out_size, void* d_ws, size_t ws_size,
                              hipStream_t stream){
  const float* x   = (const float*)d_in[0];
  const int*   t   = (const int*)  d_in[1];
  const float* tW  = (const float*)d_in[2];
  const float* tb  = (const float*)d_in[3];
  const float* W0  = (const float*)d_in[4];
  const float* b0  = (const float*)d_in[5];
  const float* W1  = (const float*)d_in[6];
  const float* b1  = (const float*)d_in[7];
  const float* W2  = (const float*)d_in[8];
  const float* b2  = (const float*)d_in[9];
  const float* W3  = (const float*)d_in[10];
  const float* b3  = (const float*)d_in[11];
  const float* res0= (const float*)d_in[12];
  const float* hW1 = (const float*)d_in[13];
  const float* hb1 = (const float*)d_in[14];
  const float* hW2 = (const float*)d_in[15];
  const float* hb2 = (const float*)d_in[16];
  short* ws  = (short*)d_ws;
  float* out = (float*)d_out;

  hipFuncSetAttribute((const void*)gcn_fused,
                      hipFuncAttributeMaxDynamicSharedMemorySize, 81920);

  prep_kernel<<<dim3((PREP_ELEMS + 255) / 256), dim3(256), 0, stream>>>(
      W0, res0, W1, W2, W3, hW1, hW2, ws);
  temb_kernel<<<dim3(512), dim3(128), 0, stream>>>(t, tW, tb, ws + OFF_TEMB);
  gcn_fused<<<dim3(16, 512), dim3(256), 81920, stream>>>(
      x, ws, b0, b1, b2, b3, hb1, hb2, out);
}

// Round 2
// 1364.084 us; speedup vs baseline: 1.2261x; 1.2261x over previous
//
#include <hip/hip_runtime.h>

// ---------------------------------------------------------------------------
// DenoiseGCN fused kernel for MI355X (gfx950) — round 2.
// R1 post-mortem: 782MB WRITE / 400MB FETCH per dispatch = scratch spill
// (acc[5][4]+afr+bfr ~= 128 VGPR cap). Fix: 8 waves x 32 cols (acc[5][2]),
// in-register ring aggregation via shfl(+-16) (gbuf deleted, LDS 40KB),
// residual in packed-bf16 registers. 16 waves/CU target.
// ---------------------------------------------------------------------------

typedef __attribute__((ext_vector_type(8))) short bf16x8;
typedef __attribute__((ext_vector_type(4))) float f32x4;

#define NV 1024

// ws element offsets (bf16 elements)
#define OFF_W0T   0        // [256][160]  K-order: [temb 128, coords 2, zeros 30]
#define OFF_RES0T 40960    // [256][160]
#define OFF_W1T   81920    // [256][256]
#define OFF_W2T   147456
#define OFF_W3T   212992
#define OFF_HW1T  278528
#define OFF_HW2T  344064   // [16][256]
#define OFF_TEMB  348160   // [512][128]
#define PREP_ELEMS 348160

__device__ __forceinline__ float bf2f(short u){
  union { unsigned int i; float f; } v;
  v.i = ((unsigned int)(unsigned short)u) << 16;
  return v.f;
}
__device__ __forceinline__ short f2bf(float f){
  union { float f; unsigned int i; } v; v.f = f;
  unsigned int r = v.i + 0x7FFFu + ((v.i >> 16) & 1u);   // RNE
  return (short)(r >> 16);
}
__device__ __forceinline__ float silu_f(float v){
  float e = __expf(-v);
  return v * __builtin_amdgcn_rcpf(1.f + e);
}
__device__ __forceinline__ f32x4 zero4(){ f32x4 z = {0.f,0.f,0.f,0.f}; return z; }

// ---------------------------------------------------------------------------
// prep: fp32 weights -> bf16, transposed to [N][K] (k contiguous) with pads.
// ---------------------------------------------------------------------------
__global__ void prep_kernel(const float* __restrict__ W0, const float* __restrict__ res0,
                            const float* __restrict__ W1, const float* __restrict__ W2,
                            const float* __restrict__ W3, const float* __restrict__ hW1,
                            const float* __restrict__ hW2, short* __restrict__ ws){
  int idx = blockIdx.x * 256 + threadIdx.x;
  if (idx >= PREP_ELEMS) return;
  float v = 0.f;
  if (idx < 81920){
    const float* src = (idx < 40960) ? W0 : res0;
    int rem = (idx < 40960) ? idx : idx - 40960;
    int n = rem / 160, k = rem - n * 160;
    if (k < 130){
      int sk = (k < 128) ? (k + 2) : (k - 128);  // temb rows first, coords last
      v = src[sk * 256 + n];
    }
  } else if (idx < 344064){
    int rem = idx - 81920;
    int seg = rem >> 16;
    int r2 = rem & 65535;
    int n = r2 >> 8, k = r2 & 255;
    const float* src = (seg == 0) ? W1 : (seg == 1) ? W2 : (seg == 2) ? W3 : hW1;
    v = src[k * 256 + n];
  } else {
    int rem = idx - 344064;
    int n = rem >> 8, k = rem & 255;
    if (n < 2) v = hW2[k * 2 + n];
  }
  ws[idx] = f2bf(v);
}

// ---------------------------------------------------------------------------
// temb: silu(sinusoidal(t) @ time_W + time_b) per batch element -> bf16
// ---------------------------------------------------------------------------
__global__ void temb_kernel(const int* __restrict__ t, const float* __restrict__ tW,
                            const float* __restrict__ tb, short* __restrict__ temb){
  __shared__ float sc[128];
  int b = blockIdx.x, n = threadIdx.x;  // 128 threads
  float tv = (float)t[b];
  {
    int j = n & 63;
    float fr = __expf(-9.210340371976184f * (float)j * (1.f / 63.f));
    float ang = tv * fr;
    sc[n] = (n < 64) ? sinf(ang) : cosf(ang);
  }
  __syncthreads();
  float acc = tb[n];
  #pragma unroll 8
  for (int k = 0; k < 128; ++k) acc += sc[k] * tW[k * 128 + n];
  temb[b * 128 + n] = f2bf(silu_f(acc));
}

// ---------------------------------------------------------------------------
// mm2: acc[mt][nt] += hb[80 x KPAD] @ Wt^T for this wave's 2 col-tiles.
// A-frag: row=l&15 (+16*mt), k=(l>>4)*8+j.  B-frag: col=l&15, same k.
// C: col=l&15, row=(l>>4)*4+j.  hb rows are 512B, XOR-swizzled per 16B chunk.
// ---------------------------------------------------------------------------
template<int KPAD>
__device__ __forceinline__ void mm2(const char* hb, const short* __restrict__ Wt,
                                    int m15, int g, int n0, f32x4 acc[5][2]){
  const short* wb = Wt + (n0 + m15) * KPAD + g * 8;
  #pragma unroll
  for (int ks = 0; ks < KPAD / 32; ++ks){
    bf16x8 bf0 = *(const bf16x8*)(wb + ks * 32);
    bf16x8 bf1 = *(const bf16x8*)(wb + 16 * KPAD + ks * 32);
    const int kb = ks * 64 + g * 16;
    #pragma unroll
    for (int mt = 0; mt < 5; ++mt){
      const int row = mt * 16 + m15;
      bf16x8 a = *(const bf16x8*)(hb + row * 512 + (kb ^ ((row & 7) << 4)));
      acc[mt][0] = __builtin_amdgcn_mfma_f32_16x16x32_bf16(a, bf0, acc[mt][0], 0, 0, 0);
      acc[mt][1] = __builtin_amdgcn_mfma_f32_16x16x32_bf16(a, bf1, acc[mt][1], 0, 0, 0);
    }
  }
}

// ---------------------------------------------------------------------------
// Fused GCN. Grid (16, 512): x = 64-vertex tile, y = batch. 512 thr = 8 waves,
// wave w owns output cols [32w, 32w+32). LDS: hbuf 80x256 bf16 = 40KB.
// Row r <-> vertex (v0 + r - 4) mod 1024; valid window shrinks 1/layer;
// out rows 4..67. Garbage rows are quarantined (matmul is row-local; agg
// only leaks garbage OUTSIDE the shrinking valid window).
// ---------------------------------------------------------------------------
__global__ __launch_bounds__(512, 4)
void gcn_fused(const float* __restrict__ x, const short* __restrict__ ws,
               const float* __restrict__ b0p, const float* __restrict__ b1p,
               const float* __restrict__ b2p, const float* __restrict__ b3p,
               const float* __restrict__ hb1p, const float* __restrict__ hb2p,
               float* __restrict__ out){
  extern __shared__ char hb[];
  const int tid = threadIdx.x;
  const int lane = tid & 63, wid = tid >> 6;
  const int m15 = lane & 15, g = lane >> 4;
  const int n0 = wid * 32;
  const int b = blockIdx.y, v0 = blockIdx.x * 64;

  // ---- stage h0: temb cols 0-127 (chunks 0-15), coords+K-pad (chunks 16-23)
  {
    const short* tembp = ws + OFF_TEMB + b * 128;
    for (int task = tid; task < 72 * 16; task += 512){
      int r = task >> 4, ck = (task & 15) * 16;
      *(bf16x8*)(hb + r * 512 + (ck ^ ((r & 7) << 4))) =
          *(const bf16x8*)(tembp + (task & 15) * 8);
    }
    // physical chunks 16..23: chunk 16^(r&7) holds [c0,c1,0...], rest zeros
    for (int task = tid; task < 80 * 8; task += 512){
      int r = task >> 3, q = task & 7;
      bf16x8 v = {0, 0, 0, 0, 0, 0, 0, 0};
      if (q == (r & 7) && r < 72){
        int vtx = (v0 + r - 4) & (NV - 1);
        const float* cp = x + b * 2048 + vtx * 2;
        v[0] = f2bf(cp[0]);
        v[1] = f2bf(cp[1]);
      }
      *(bf16x8*)(hb + r * 512 + (16 + q) * 16) = v;
    }
  }
  __syncthreads();

  f32x4 acc[5][2];
  unsigned int hreg[5][2][2];   // packed bf16 residual, this wave's elements

  // ---- layer 0: g = h0@W0, res = h0@res0 (regs); h1 = silu(agg+b0+res) ----
  {
    f32x4 accr[5][2];
    #pragma unroll
    for (int mt = 0; mt < 5; ++mt){
      acc[mt][0] = zero4(); acc[mt][1] = zero4();
      accr[mt][0] = zero4(); accr[mt][1] = zero4();
    }
    mm2<160>(hb, ws + OFF_W0T, m15, g, n0, acc);
    mm2<160>(hb, ws + OFF_RES0T, m15, g, n0, accr);
    __syncthreads();
    const float bias[2] = { b0p[n0 + m15], b0p[n0 + 16 + m15] };
    #pragma unroll
    for (int mt = 0; mt < 5; ++mt)
      #pragma unroll
      for (int nt = 0; nt < 2; ++nt){
        float a0 = acc[mt][nt][0], a1 = acc[mt][nt][1];
        float a2 = acc[mt][nt][2], a3 = acc[mt][nt][3];
        // row-1 for j=0 comes from lane-16; source pre-selects mt-1 at g==3
        float upv = (g == 3) ? acc[mt > 0 ? mt - 1 : 0][nt][3] : a3;
        float pm0 = __shfl(upv, (lane + 48) & 63);
        float dnv = (g == 0) ? acc[mt < 4 ? mt + 1 : 4][nt][0] : a0;
        float pp3 = __shfl(dnv, (lane + 16) & 63);
        float base = bias[nt];
        float s0 = (pm0 + a0 + a1) * (1.f / 3.f) + base + accr[mt][nt][0];
        float s1 = (a0 + a1 + a2) * (1.f / 3.f) + base + accr[mt][nt][1];
        float s2 = (a1 + a2 + a3) * (1.f / 3.f) + base + accr[mt][nt][2];
        float s3 = (a2 + a3 + pp3) * (1.f / 3.f) + base + accr[mt][nt][3];
        unsigned short q0 = (unsigned short)f2bf(silu_f(s0));
        unsigned short q1 = (unsigned short)f2bf(silu_f(s1));
        unsigned short q2 = (unsigned short)f2bf(silu_f(s2));
        unsigned short q3 = (unsigned short)f2bf(silu_f(s3));
        const int row = mt * 16 + g * 4;
        const int cb = (n0 + nt * 16 + m15) * 2;
        *(short*)(hb + (row    ) * 512 + (cb ^ (((row    ) & 7) << 4))) = (short)q0;
        *(short*)(hb + (row + 1) * 512 + (cb ^ (((row + 1) & 7) << 4))) = (short)q1;
        *(short*)(hb + (row + 2) * 512 + (cb ^ (((row + 2) & 7) << 4))) = (short)q2;
        *(short*)(hb + (row + 3) * 512 + (cb ^ (((row + 3) & 7) << 4))) = (short)q3;
        hreg[mt][nt][0] = (unsigned int)q0 | ((unsigned int)q1 << 16);
        hreg[mt][nt][1] = (unsigned int)q2 | ((unsigned int)q3 << 16);
      }
  }
  __syncthreads();

  // ---- layers 1..3: h = silu(agg(h@W)/3 + b + h) ----
  #pragma unroll
  for (int L = 0; L < 3; ++L){
    const short* Wt = ws + (L == 0 ? OFF_W1T : L == 1 ? OFF_W2T : OFF_W3T);
    const float* bp = (L == 0 ? b1p : L == 1 ? b2p : b3p);
    #pragma unroll
    for (int mt = 0; mt < 5; ++mt){ acc[mt][0] = zero4(); acc[mt][1] = zero4(); }
    mm2<256>(hb, Wt, m15, g, n0, acc);
    __syncthreads();
    const float bias[2] = { bp[n0 + m15], bp[n0 + 16 + m15] };
    #pragma unroll
    for (int mt = 0; mt < 5; ++mt)
      #pragma unroll
      for (int nt = 0; nt < 2; ++nt){
        float a0 = acc[mt][nt][0], a1 = acc[mt][nt][1];
        float a2 = acc[mt][nt][2], a3 = acc[mt][nt][3];
        float upv = (g == 3) ? acc[mt > 0 ? mt - 1 : 0][nt][3] : a3;
        float pm0 = __shfl(upv, (lane + 48) & 63);
        float dnv = (g == 0) ? acc[mt < 4 ? mt + 1 : 4][nt][0] : a0;
        float pp3 = __shfl(dnv, (lane + 16) & 63);
        float base = bias[nt];
        float r0 = bf2f((short)(hreg[mt][nt][0] & 0xffff));
        float r1 = bf2f((short)(hreg[mt][nt][0] >> 16));
        float r2 = bf2f((short)(hreg[mt][nt][1] & 0xffff));
        float r3 = bf2f((short)(hreg[mt][nt][1] >> 16));
        float s0 = (pm0 + a0 + a1) * (1.f / 3.f) + base + r0;
        float s1 = (a0 + a1 + a2) * (1.f / 3.f) + base + r1;
        float s2 = (a1 + a2 + a3) * (1.f / 3.f) + base + r2;
        float s3 = (a2 + a3 + pp3) * (1.f / 3.f) + base + r3;
        unsigned short q0 = (unsigned short)f2bf(silu_f(s0));
        unsigned short q1 = (unsigned short)f2bf(silu_f(s1));
        unsigned short q2 = (unsigned short)f2bf(silu_f(s2));
        unsigned short q3 = (unsigned short)f2bf(silu_f(s3));
        const int row = mt * 16 + g * 4;
        const int cb = (n0 + nt * 16 + m15) * 2;
        *(short*)(hb + (row    ) * 512 + (cb ^ (((row    ) & 7) << 4))) = (short)q0;
        *(short*)(hb + (row + 1) * 512 + (cb ^ (((row + 1) & 7) << 4))) = (short)q1;
        *(short*)(hb + (row + 2) * 512 + (cb ^ (((row + 2) & 7) << 4))) = (short)q2;
        *(short*)(hb + (row + 3) * 512 + (cb ^ (((row + 3) & 7) << 4))) = (short)q3;
        hreg[mt][nt][0] = (unsigned int)q0 | ((unsigned int)q1 << 16);
        hreg[mt][nt][1] = (unsigned int)q2 | ((unsigned int)q3 << 16);
      }
    __syncthreads();
  }

  // ---- head part 1: u = silu(h4 @ hW1 + hb1), in place ----
  {
    #pragma unroll
    for (int mt = 0; mt < 5; ++mt){ acc[mt][0] = zero4(); acc[mt][1] = zero4(); }
    mm2<256>(hb, ws + OFF_HW1T, m15, g, n0, acc);
    __syncthreads();
    const float bias[2] = { hb1p[n0 + m15], hb1p[n0 + 16 + m15] };
    #pragma unroll
    for (int mt = 0; mt < 5; ++mt)
      #pragma unroll
      for (int nt = 0; nt < 2; ++nt){
        const int row = mt * 16 + g * 4;
        const int cb = (n0 + nt * 16 + m15) * 2;
        #pragma unroll
        for (int j = 0; j < 4; ++j){
          short q = f2bf(silu_f(acc[mt][nt][j] + bias[nt]));
          *(short*)(hb + (row + j) * 512 + (cb ^ (((row + j) & 7) << 4))) = q;
        }
      }
    __syncthreads();
  }

  // ---- head part 2 (wave 0 only): out = u @ hW2 + hb2, rows 4..67 ----
  if (wid == 0){
    f32x4 a2[5];
    #pragma unroll
    for (int mt = 0; mt < 5; ++mt) a2[mt] = zero4();
    const short* wb = ws + OFF_HW2T + m15 * 256 + g * 8;
    #pragma unroll
    for (int ks = 0; ks < 8; ++ks){
      bf16x8 bfr = *(const bf16x8*)(wb + ks * 32);
      const int kb = ks * 64 + g * 16;
      #pragma unroll
      for (int mt = 0; mt < 5; ++mt){
        const int row = mt * 16 + m15;
        bf16x8 a = *(const bf16x8*)(hb + row * 512 + (kb ^ ((row & 7) << 4)));
        a2[mt] = __builtin_amdgcn_mfma_f32_16x16x32_bf16(a, bfr, a2[mt], 0, 0, 0);
      }
    }
    if (m15 < 2){
      float bias = hb2p[m15];
      #pragma unroll
      for (int mt = 0; mt < 5; ++mt)
        #pragma unroll
        for (int j = 0; j < 4; ++j){
          int row = mt * 16 + g * 4 + j;
          if (row >= 4 && row < 68)
            out[b * 2048 + (v0 + row - 4) * 2 + m15] = a2[mt][j] + bias;
        }
    }
  }
}

// ---------------------------------------------------------------------------
extern "C" void kernel_launch(void* const* d_in, const int* in_sizes, int n_in,
                              void* d_out, int out_size, void* d_ws, size_t ws_size,
                              hipStream_t stream){
  const float* x   = (const float*)d_in[0];
  const int*   t   = (const int*)  d_in[1];
  const float* tW  = (const float*)d_in[2];
  const float* tb  = (const float*)d_in[3];
  const float* W0  = (const float*)d_in[4];
  const float* b0  = (const float*)d_in[5];
  const float* W1  = (const float*)d_in[6];
  const float* b1  = (const float*)d_in[7];
  const float* W2  = (const float*)d_in[8];
  const float* b2  = (const float*)d_in[9];
  const float* W3  = (const float*)d_in[10];
  const float* b3  = (const float*)d_in[11];
  const float* res0= (const float*)d_in[12];
  const float* hW1 = (const float*)d_in[13];
  const float* hb1 = (const float*)d_in[14];
  const float* hW2 = (const float*)d_in[15];
  const float* hb2 = (const float*)d_in[16];
  short* ws  = (short*)d_ws;
  float* out = (float*)d_out;

  hipFuncSetAttribute((const void*)gcn_fused,
                      hipFuncAttributeMaxDynamicSharedMemorySize, 40960);

  prep_kernel<<<dim3((PREP_ELEMS + 255) / 256), dim3(256), 0, stream>>>(
      W0, res0, W1, W2, W3, hW1, hW2, ws);
  temb_kernel<<<dim3(512), dim3(128), 0, stream>>>(t, tW, tb, ws + OFF_TEMB);
  gcn_fused<<<dim3(16, 512), dim3(512), 40960, stream>>>(
      x, ws, b0, b1, b2, b3, hb1, hb2, out);
}